// Round 1
// baseline (1386.140 us; speedup 1.0000x reference)
//
#include <hip/hip_runtime.h>

// LinearAttention: out = Z + ((P@Z)@M @ (Z^T @ (Q@Z))) / N
// M[r,c] = 0.9^(r-c) lower-triangular (r,c < 4096)  -> reverse suffix scan.
// Pipeline (all bf16 MFMA GEMMs, padded 4097->4224):
//   b0 = Pb (cast P)          b4 = Qb (cast Q)       b1 = Zt (transpose-cast Z)
//   b2 = PZ   = gemm(Pb, Zt)
//   b3 = left = decay_scan(PZ)
//   b0 = QZ   = gemm(Qb, Zt)       (overwrites Pb)
//   b2 = QZt  = transpose(QZ)      (overwrites PZ)
//   b0 = rightT = gemm(QZt, Zt)    (rightT = (QZ)^T @ Z = (Z^T Q Z)^T)
//   out = Z + gemm(left, rightT)/4096

typedef __attribute__((ext_vector_type(8))) short short8;
typedef __attribute__((ext_vector_type(4))) float f32x4;
typedef __attribute__((ext_vector_type(4))) unsigned short u16x4;

#define NPAD 4224   // 33 * 128
#define NV   4097   // valid rows/cols (2D+1 == H)
#define NCTX 4096   // N (context length, decay mask cutoff)

__device__ __forceinline__ float b2f(unsigned short u) {
  return __uint_as_float(((unsigned)u) << 16);
}
__device__ __forceinline__ unsigned short f2b(float f) {
  unsigned b = __float_as_uint(f);
  return (unsigned short)((b + 0x7FFFu + ((b >> 16) & 1u)) >> 16);
}

__device__ __forceinline__ void gload16(const void* g, void* l) {
  __builtin_amdgcn_global_load_lds(
      (const __attribute__((address_space(1))) unsigned int*)g,
      (__attribute__((address_space(3))) unsigned int*)l, 16, 0, 0);
}

// ---------------- cast + zero-pad: f32 [4097x4097] -> bf16 [4224x4224] --------
__global__ __launch_bounds__(256) void cast_pad(const float* __restrict__ in,
                                                unsigned short* __restrict__ out) {
  int idx = blockIdx.x * 256 + threadIdx.x;          // 4224 * 1056 total
  int r = idx / 1056;
  int c4 = (idx - r * 1056) * 4;
  u16x4 o = {0, 0, 0, 0};
  if (r < NV) {
    const float* p = in + (size_t)r * NV + c4;
#pragma unroll
    for (int j = 0; j < 4; ++j) {
      float v = (c4 + j < NV) ? p[j] : 0.f;
      o[j] = f2b(v);
    }
  }
  *(u16x4*)&out[(size_t)r * NPAD + c4] = o;
}

// ------------- transpose-cast: f32 [4097x4097] -> bf16^T [4224x4224] ----------
__global__ __launch_bounds__(256) void transpose_cast(const float* __restrict__ in,
                                                      unsigned short* __restrict__ out) {
  __shared__ float tile[32][33];
  int x = threadIdx.x & 31;
  int y = threadIdx.x >> 5;  // 0..7
  int bx = blockIdx.x, by = blockIdx.y;
  int ic = bx * 32 + x;
#pragma unroll
  for (int j = 0; j < 4; ++j) {
    int ir = by * 32 + y + j * 8;
    float v = (ir < NV && ic < NV) ? in[(size_t)ir * NV + ic] : 0.f;
    tile[y + j * 8][x] = v;
  }
  __syncthreads();
  int orow = bx * 32;
  int ocol = by * 32 + x;
#pragma unroll
  for (int j = 0; j < 4; ++j) {
    out[(size_t)(orow + y + j * 8) * NPAD + ocol] = f2b(tile[x][y + j * 8]);
  }
}

// ------------- transpose bf16 [4224x4224] -> bf16 [4224x4224] -----------------
__global__ __launch_bounds__(256) void transpose_b16(const unsigned short* __restrict__ in,
                                                     unsigned short* __restrict__ out) {
  __shared__ unsigned short tile[32][33];
  int x = threadIdx.x & 31;
  int y = threadIdx.x >> 5;
  int bx = blockIdx.x, by = blockIdx.y;
  int ic = bx * 32 + x;
#pragma unroll
  for (int j = 0; j < 4; ++j) {
    int ir = by * 32 + y + j * 8;
    tile[y + j * 8][x] = in[(size_t)ir * NPAD + ic];
  }
  __syncthreads();
  int orow = bx * 32;
  int ocol = by * 32 + x;
#pragma unroll
  for (int j = 0; j < 4; ++j) {
    out[(size_t)(orow + y + j * 8) * NPAD + ocol] = tile[x][y + j * 8];
  }
}

// ------------- decay scan: left[:,c] = sum_{r>=c}^{4095} 0.9^(r-c) PZ[:,r] ----
// one wave per (row, 64-col chunk); own-chunk shuffle suffix-scan + 4 carry chunks
// (0.9^256 ~ 2e-12 -> truncation negligible)
__global__ __launch_bounds__(256) void decay_scan(const unsigned short* __restrict__ PZ,
                                                  unsigned short* __restrict__ L) {
  const int wid = (blockIdx.x << 2) | ((int)threadIdx.x >> 6);
  const int lane = threadIdx.x & 63;
  const int row = wid / 66;
  const int cj = wid - row * 66;
  const int c0 = cj * 64;

  const float l2l = -0.15200309344504995f;  // log2(0.9)
  const float pl = exp2f((float)lane * l2l);           // 0.9^lane
  const float plc = exp2f((float)(64 - lane) * l2l);   // 0.9^(64-lane)

  const unsigned short* prow = PZ + (size_t)row * NPAD;
  float x[5];
#pragma unroll
  for (int d = 0; d < 5; ++d) {
    int c = c0 + d * 64 + lane;
    x[d] = (c < NCTX) ? b2f(prow[c]) : 0.f;
  }
  // weighted suffix scan within own chunk: s_k = sum_{m>=k} 0.9^(m-k) x_m
  float s = x[0];
  const float pw[6] = {0.9f, 0.81f, 0.6561f, 0.43046721f,
                       0.18530201888518410f, 0.03433683820292512f};
#pragma unroll
  for (int i = 0; i < 6; ++i) {
    int tt = 1 << i;
    float o = __shfl_down(s, tt);
    s += (lane + tt < 64) ? pw[i] * o : 0.f;
  }
  // carry from next 4 chunks: carry = sum_d 0.9^(64(d-1)) * S_d
  const float cw[4] = {1.f, 1.1790184577738583e-3f, 1.3900845237714557e-6f,
                       1.6389541800e-9f};
  float carry = 0.f;
#pragma unroll
  for (int d = 1; d <= 4; ++d) {
    float v = x[d] * pl;
#pragma unroll
    for (int i = 0; i < 6; ++i) v += __shfl_xor(v, 1 << i);
    carry += cw[d - 1] * v;
  }
  float left = s + plc * carry;
  L[(size_t)row * NPAD + c0 + lane] = f2b(left);
}

// ------------- bf16 GEMM, C[m][n] = sum_k A[m][k] * Bt[n][k] ------------------
// 128x128 tile, BK=64, 4 waves (2x2, 64x64 each), 16x16x32 MFMA, m97 structure.
// MODE 0: store bf16 into Cb (padded).  MODE 1: Cf = Zin + acc/4096 (valid region).
template <int MODE>
__global__ __launch_bounds__(256) void gemm_bt(const unsigned short* __restrict__ A,
                                               const unsigned short* __restrict__ Bt,
                                               unsigned short* __restrict__ Cb,
                                               float* __restrict__ Cf,
                                               const float* __restrict__ Zin) {
  __shared__ __align__(16) unsigned short As[128 * 64];
  __shared__ __align__(16) unsigned short Bs[128 * 64];

  const int t = threadIdx.x;
  const int lane = t & 63;
  const int w = t >> 6;
  const int wr = w >> 1, wc = w & 1;
  const int q = lane >> 4, r16 = lane & 15;
  const int brow = blockIdx.y * 128, bcol = blockIdx.x * 128;

  f32x4 acc[4][4] = {};

  const int lr = lane >> 3;        // staging row-within-8
  const int c8 = (lane & 7) * 8;   // staging k-offset (elements)

  for (int K0 = 0; K0 < NPAD; K0 += 64) {
#pragma unroll
    for (int it = 0; it < 4; ++it) {
      const int rb = (w * 4 + it) * 8;  // 8 rows per gload instruction
      gload16(A + (size_t)(brow + rb + lr) * NPAD + K0 + c8, &As[rb * 64]);
      gload16(Bt + (size_t)(bcol + rb + lr) * NPAD + K0 + c8, &Bs[rb * 64]);
    }
    __syncthreads();  // drains vmcnt -> staged data visible
#pragma unroll
    for (int kk = 0; kk < 64; kk += 32) {
      short8 a[4], b[4];
#pragma unroll
      for (int m = 0; m < 4; ++m)
        a[m] = *(const short8*)&As[(wr * 64 + m * 16 + r16) * 64 + kk + q * 8];
#pragma unroll
      for (int n = 0; n < 4; ++n)
        b[n] = *(const short8*)&Bs[(wc * 64 + n * 16 + r16) * 64 + kk + q * 8];
#pragma unroll
      for (int m = 0; m < 4; ++m)
#pragma unroll
        for (int n = 0; n < 4; ++n)
          acc[m][n] = __builtin_amdgcn_mfma_f32_16x16x32_bf16(a[m], b[n], acc[m][n], 0, 0, 0);
    }
    __syncthreads();  // protect LDS before next stage
  }

#pragma unroll
  for (int m = 0; m < 4; ++m) {
    const int row = brow + wr * 64 + m * 16 + q * 4;  // C/D: col=lane&15, row=(lane>>4)*4+reg
#pragma unroll
    for (int n = 0; n < 4; ++n) {
      const int col = bcol + wc * 64 + n * 16 + r16;
#pragma unroll
      for (int rr = 0; rr < 4; ++rr) {
        float v = acc[m][n][rr];
        if (MODE == 0) {
          Cb[(size_t)(row + rr) * NPAD + col] = f2b(v);
        } else {
          int rg = row + rr;
          if (rg < NV && col < NV) {
            size_t o = (size_t)rg * NV + col;
            Cf[o] = Zin[o] + v * (1.0f / 4096.0f);
          }
        }
      }
    }
  }
}

extern "C" void kernel_launch(void* const* d_in, const int* in_sizes, int n_in,
                              void* d_out, int out_size, void* d_ws, size_t ws_size,
                              hipStream_t stream) {
  (void)in_sizes; (void)n_in; (void)out_size; (void)ws_size;
  const float* Z = (const float*)d_in[0];
  const float* P = (const float*)d_in[1];
  const float* Q = (const float*)d_in[2];
  float* out = (float*)d_out;

  const size_t SZ = (size_t)NPAD * NPAD;  // elements per scratch matrix
  unsigned short* b0 = (unsigned short*)d_ws;
  unsigned short* b1 = b0 + SZ;
  unsigned short* b2 = b1 + SZ;
  unsigned short* b3 = b2 + SZ;
  unsigned short* b4 = b3 + SZ;
  // total ws use: 5 * 4224^2 * 2B = 178.4 MB

  dim3 blk(256);
  dim3 gt(132, 132);
  dim3 gg(33, 33);

  cast_pad<<<17424, blk, 0, stream>>>(P, b0);               // b0 = Pb
  cast_pad<<<17424, blk, 0, stream>>>(Q, b4);               // b4 = Qb
  transpose_cast<<<gt, blk, 0, stream>>>(Z, b1);            // b1 = Zt
  gemm_bt<0><<<gg, blk, 0, stream>>>(b0, b1, b2, nullptr, nullptr);  // b2 = PZ
  decay_scan<<<69696, blk, 0, stream>>>(b2, b3);            // b3 = left
  gemm_bt<0><<<gg, blk, 0, stream>>>(b4, b1, b0, nullptr, nullptr);  // b0 = QZ
  transpose_b16<<<gt, blk, 0, stream>>>(b0, b2);            // b2 = QZt
  gemm_bt<0><<<gg, blk, 0, stream>>>(b2, b1, b0, nullptr, nullptr);  // b0 = rightT
  gemm_bt<1><<<gg, blk, 0, stream>>>(b3, b0, nullptr, out, Z);       // out
}

// Round 2
// 1086.428 us; speedup vs baseline: 1.2759x; 1.2759x over previous
//
#include <hip/hip_runtime.h>

// out = Z + ((P@Z)@M @ (Z^T @ (Q@Z))) / N ; M[r,c]=0.9^(r-c) lower-tri (r,c<4096)
// Pipeline (bf16 MFMA, padded 4097->4352 = 17*256):
//   b0=Pb, b3=Qb, b1=Zt
//   dual gemm: PZ->b2, QZ->dox(d_out scratch)
//   QZt = transpose(dox) -> b3 ; left = decay_scan(b2) -> b0
//   rightT = gemm(b3, b1) -> b2
//   out = Z + gemm(b0, b2)/4096 -> d_out (f32)

typedef __attribute__((ext_vector_type(8))) short short8;
typedef __attribute__((ext_vector_type(4))) float f32x4;
typedef __attribute__((ext_vector_type(4))) unsigned short u16x4;

#define NPAD 4352   // 17 * 256
#define NV   4097
#define NCTX 4096
#define NT   68     // K-tiles of 64

__device__ __forceinline__ float b2f(unsigned short u) {
  return __uint_as_float(((unsigned)u) << 16);
}
__device__ __forceinline__ unsigned short f2b(float f) {
  unsigned b = __float_as_uint(f);
  return (unsigned short)((b + 0x7FFFu + ((b >> 16) & 1u)) >> 16);
}
__device__ __forceinline__ void gload16(const void* g, void* l) {
  __builtin_amdgcn_global_load_lds(
      (const __attribute__((address_space(1))) unsigned int*)g,
      (__attribute__((address_space(3))) unsigned int*)l, 16, 0, 0);
}

// ---------------- cast + zero-pad: f32 [4097x4097] -> bf16 [4352x4352] --------
__global__ __launch_bounds__(256) void cast_pad(const float* __restrict__ in,
                                                unsigned short* __restrict__ out) {
  int idx = blockIdx.x * 256 + threadIdx.x;  // 4352 * 1088 quads
  int r = idx / 1088;
  int c4 = (idx - r * 1088) * 4;
  u16x4 o = {0, 0, 0, 0};
  if (r < NV) {
    const float* p = in + (size_t)r * NV + c4;
#pragma unroll
    for (int j = 0; j < 4; ++j) {
      float v = (c4 + j < NV) ? p[j] : 0.f;
      o[j] = f2b(v);
    }
  }
  *(u16x4*)&out[(size_t)r * NPAD + c4] = o;
}

// ------------- transpose-cast: f32 [4097x4097] -> bf16^T [4352x4352] ----------
__global__ __launch_bounds__(256) void transpose_cast(const float* __restrict__ in,
                                                      unsigned short* __restrict__ out) {
  __shared__ float tile[32][33];
  int x = threadIdx.x & 31;
  int y = threadIdx.x >> 5;
  int bx = blockIdx.x, by = blockIdx.y;
  int ic = bx * 32 + x;
#pragma unroll
  for (int j = 0; j < 4; ++j) {
    int ir = by * 32 + y + j * 8;
    float v = (ir < NV && ic < NV) ? in[(size_t)ir * NV + ic] : 0.f;
    tile[y + j * 8][x] = v;
  }
  __syncthreads();
  int orow = bx * 32;
  int ocol = by * 32 + x;
#pragma unroll
  for (int j = 0; j < 4; ++j) {
    out[(size_t)(orow + y + j * 8) * NPAD + ocol] = f2b(tile[x][y + j * 8]);
  }
}

// ------------- transpose bf16 [4352x4352] ------------------------------------
__global__ __launch_bounds__(256) void transpose_b16(const unsigned short* __restrict__ in,
                                                     unsigned short* __restrict__ out) {
  __shared__ unsigned short tile[32][33];
  int x = threadIdx.x & 31;
  int y = threadIdx.x >> 5;
  int bx = blockIdx.x, by = blockIdx.y;
  int ic = bx * 32 + x;
#pragma unroll
  for (int j = 0; j < 4; ++j) {
    int ir = by * 32 + y + j * 8;
    tile[y + j * 8][x] = in[(size_t)ir * NPAD + ic];
  }
  __syncthreads();
  int orow = bx * 32;
  int ocol = by * 32 + x;
#pragma unroll
  for (int j = 0; j < 4; ++j) {
    out[(size_t)(orow + y + j * 8) * NPAD + ocol] = tile[x][y + j * 8];
  }
}

// ------------- decay scan: left[:,c] = sum_{r>=c}^{4095} 0.9^(r-c) PZ[:,r] ----
__global__ __launch_bounds__(256) void decay_scan(const unsigned short* __restrict__ PZ,
                                                  unsigned short* __restrict__ L) {
  const int wid = (blockIdx.x << 2) | ((int)threadIdx.x >> 6);
  const int lane = threadIdx.x & 63;
  const int row = wid / 68;
  const int cj = wid - row * 68;
  const int c0 = cj * 64;

  const float l2l = -0.15200309344504995f;  // log2(0.9)
  const float pl = exp2f((float)lane * l2l);
  const float plc = exp2f((float)(64 - lane) * l2l);

  const unsigned short* prow = PZ + (size_t)row * NPAD;
  float x[5];
#pragma unroll
  for (int d = 0; d < 5; ++d) {
    int c = c0 + d * 64 + lane;
    x[d] = (c < NCTX) ? b2f(prow[c]) : 0.f;
  }
  float s = x[0];
  const float pw[6] = {0.9f, 0.81f, 0.6561f, 0.43046721f,
                       0.18530201888518410f, 0.03433683820292512f};
#pragma unroll
  for (int i = 0; i < 6; ++i) {
    int tt = 1 << i;
    float o = __shfl_down(s, tt);
    s += (lane + tt < 64) ? pw[i] * o : 0.f;
  }
  const float cw[4] = {1.f, 1.1790184577738583e-3f, 1.3900845237714557e-6f,
                       1.6389541800e-9f};
  float carry = 0.f;
#pragma unroll
  for (int d = 1; d <= 4; ++d) {
    float v = x[d] * pl;
#pragma unroll
    for (int i = 0; i < 6; ++i) v += __shfl_xor(v, 1 << i);
    carry += cw[d - 1] * v;
  }
  float left = s + plc * carry;
  L[(size_t)row * NPAD + c0 + lane] = f2b(left);
}

// ------------- 256x256 8-phase bf16 GEMM: C = A @ Bt^T ------------------------
// 8 waves (2x4), per-wave 128x64, BK=64, 128KB LDS dbuf, counted vmcnt(4),
// XOR bank swizzle (pre-swizzled global src + swizzled ds_read), setprio, XCD swz.
// MODE 0: Cb bf16 (batch via A2/Cb2).  MODE 1: Cf = Zin + acc/4096.
template <int MODE>
__global__ __launch_bounds__(512, 2) void gemm256(
    const unsigned short* __restrict__ A, const unsigned short* __restrict__ Bt,
    unsigned short* __restrict__ Cb, float* __restrict__ Cf,
    const float* __restrict__ Zin,
    const unsigned short* __restrict__ A2, unsigned short* __restrict__ Cb2,
    int nwg) {
  __shared__ __align__(16) unsigned short Asm[2][256 * 64];
  __shared__ __align__(16) unsigned short Bsm[2][256 * 64];

  const int tid = threadIdx.x;
  const int lane = tid & 63;
  const int w = tid >> 6;
  const int wr = w >> 2, wc = w & 3;
  const int q = lane >> 4, r16 = lane & 15;

  // bijective XCD swizzle (m204)
  int orig = blockIdx.x;
  int qq = nwg >> 3, rr8 = nwg & 7;
  int xcd = orig & 7, idx = orig >> 3;
  int wg = (xcd < rr8 ? xcd * (qq + 1) : rr8 * (qq + 1) + (xcd - rr8) * qq) + idx;
  int batch = 0;
  if (wg >= 289) { batch = 1; wg -= 289; }
  const int by = wg / 17, bx = wg - by * 17;
  const int brow = by * 256, bcol = bx * 256;

  const unsigned short* Am = batch ? A2 : A;
  unsigned short* Co = batch ? Cb2 : Cb;

  // staging: linear LDS dest (global_load_lds), inverse-swizzled global source.
  auto stageA = [&](int ktile, int mq, int bb) {
#pragma unroll
    for (int it = 0; it < 2; ++it) {
      int sub = w * 16 + it * 8;
      int row0 = mq * 64 + sub + (sub & 64);      // rows {mq*64..+63} U {128+mq*64..+63}
      int row = row0 + (lane >> 3);
      int win = (lane & 7) ^ (row & 7);
      gload16(Am + (size_t)(brow + row) * NPAD + ktile * 64 + win * 8,
              &Asm[bb][row0 * 64]);
    }
  };
  auto stageB = [&](int ktile, int nq, int bb) {
#pragma unroll
    for (int it = 0; it < 2; ++it) {
      int sub = w * 16 + it * 8;
      int row0 = ((sub >> 5) << 6) + nq * 32 + (sub & 31);  // {g*64+nq*32 .. +31}
      int row = row0 + (lane >> 3);
      int win = (lane & 7) ^ (row & 7);
      gload16(Bt + (size_t)(bcol + row) * NPAD + ktile * 64 + win * 8,
              &Bsm[bb][row0 * 64]);
    }
  };

  short8 a[4][2], b0r[2][2], b1r[2][2];
  auto rdA = [&](int mq, int bb) {
#pragma unroll
    for (int m = 0; m < 4; ++m) {
      int row = wr * 128 + mq * 64 + m * 16 + r16;
#pragma unroll
      for (int kk = 0; kk < 2; ++kk) {
        int win = (q + kk * 4) ^ (r16 & 7);
        a[m][kk] = *(const short8*)&Asm[bb][row * 64 + win * 8];
      }
    }
  };
  auto rdB = [&](short8 (&b)[2][2], int nq, int bb) {
#pragma unroll
    for (int n = 0; n < 2; ++n) {
      int row = wc * 64 + nq * 32 + n * 16 + r16;
#pragma unroll
      for (int kk = 0; kk < 2; ++kk) {
        int win = (q + kk * 4) ^ (r16 & 7);
        b[n][kk] = *(const short8*)&Bsm[bb][row * 64 + win * 8];
      }
    }
  };

  f32x4 acc[8][4] = {};

  auto mma = [&](short8 (&b)[2][2], int mq, int nq) {
    __builtin_amdgcn_s_setprio(1);
#pragma unroll
    for (int kk = 0; kk < 2; ++kk)
#pragma unroll
      for (int m = 0; m < 4; ++m)
#pragma unroll
        for (int n = 0; n < 2; ++n)
          acc[mq * 4 + m][nq * 2 + n] = __builtin_amdgcn_mfma_f32_16x16x32_bf16(
              a[m][kk], b[n][kk], acc[mq * 4 + m][nq * 2 + n], 0, 0, 0);
    __builtin_amdgcn_s_setprio(0);
  };

  // prologue: tile0 fully -> buf0 ; tile1 {A0,B0} -> buf1 ; drain tile0.
  stageA(0, 0, 0); stageB(0, 0, 0); stageA(0, 1, 0); stageB(0, 1, 0);
  stageA(1, 0, 1); stageB(1, 0, 1);
  asm volatile("s_waitcnt vmcnt(4)" ::: "memory");
  __builtin_amdgcn_s_barrier();

  for (int kt = 0; kt < NT; ++kt) {
    const int bb = kt & 1;
    // G1 (mq0,nq0): 12 ds_reads; stage A1,B1(kt+1) -> bb^1
    rdA(0, bb);
    rdB(b0r, 0, bb);
    if (kt + 1 < NT) { stageA(kt + 1, 1, bb ^ 1); stageB(kt + 1, 1, bb ^ 1); }
    __builtin_amdgcn_s_barrier();
    mma(b0r, 0, 0);
    __builtin_amdgcn_s_barrier();
    // G2 (mq0,nq1): 4 ds_reads
    rdB(b1r, 1, bb);
    __builtin_amdgcn_s_barrier();
    mma(b1r, 0, 1);
    __builtin_amdgcn_s_barrier();
    // G3 (mq1,nq0): 8 ds_reads; stage A0(kt+2) -> bb
    rdA(1, bb);
    if (kt + 2 < NT) stageA(kt + 2, 0, bb);
    __builtin_amdgcn_s_barrier();
    mma(b0r, 1, 0);
    __builtin_amdgcn_s_barrier();
    // G4 (mq1,nq1): stage B0(kt+2) -> bb; counted drain; barrier
    if (kt + 2 < NT) stageB(kt + 2, 0, bb);
    if (kt < NT - 2) { asm volatile("s_waitcnt vmcnt(4)" ::: "memory"); }
    else             { asm volatile("s_waitcnt vmcnt(0)" ::: "memory"); }
    __builtin_amdgcn_s_barrier();
    mma(b1r, 1, 1);
    __builtin_amdgcn_s_barrier();
  }

#pragma unroll
  for (int m = 0; m < 8; ++m) {
    const int row = brow + wr * 128 + m * 16 + q * 4;
#pragma unroll
    for (int n = 0; n < 4; ++n) {
      const int col = bcol + wc * 64 + n * 16 + r16;
#pragma unroll
      for (int v = 0; v < 4; ++v) {
        float val = acc[m][n][v];
        if (MODE == 0) {
          Co[(size_t)(row + v) * NPAD + col] = f2b(val);
        } else {
          int rg = row + v;
          if (rg < NV && col < NV) {
            size_t o = (size_t)rg * NV + col;
            Cf[o] = Zin[o] + val * (1.0f / 4096.0f);
          }
        }
      }
    }
  }
}

extern "C" void kernel_launch(void* const* d_in, const int* in_sizes, int n_in,
                              void* d_out, int out_size, void* d_ws, size_t ws_size,
                              hipStream_t stream) {
  (void)in_sizes; (void)n_in; (void)out_size; (void)ws_size;
  const float* Z = (const float*)d_in[0];
  const float* P = (const float*)d_in[1];
  const float* Q = (const float*)d_in[2];
  float* out = (float*)d_out;

  const size_t SZ = (size_t)NPAD * NPAD;
  unsigned short* b0 = (unsigned short*)d_ws;          // Pb -> left
  unsigned short* b1 = b0 + SZ;                        // Zt
  unsigned short* b2 = b1 + SZ;                        // PZ -> rightT
  unsigned short* b3 = b2 + SZ;                        // Qb -> QZt
  unsigned short* dox = (unsigned short*)d_out;        // QZ scratch (d_out, 67MB >= 37.9MB)

  dim3 blk(256), blk5(512);
  dim3 gt(136, 136);

  cast_pad<<<18496, blk, 0, stream>>>(P, b0);
  cast_pad<<<18496, blk, 0, stream>>>(Q, b3);
  transpose_cast<<<gt, blk, 0, stream>>>(Z, b1);
  // dual gemm: PZ = Pb@Z -> b2 ; QZ = Qb@Z -> dox
  gemm256<0><<<578, blk5, 0, stream>>>(b0, b1, b2, nullptr, nullptr, b3, dox, 578);
  transpose_b16<<<gt, blk, 0, stream>>>(dox, b3);      // QZt
  decay_scan<<<73984, blk, 0, stream>>>(b2, b0);       // left
  gemm256<0><<<289, blk5, 0, stream>>>(b3, b1, b2, nullptr, nullptr, nullptr, nullptr, 289);  // rightT
  gemm256<1><<<289, blk5, 0, stream>>>(b0, b2, nullptr, out, Z, nullptr, nullptr, 289);       // out
}